// Round 9
// baseline (275.768 us; speedup 1.0000x reference)
//
#include <hip/hip_runtime.h>
#include <stdint.h>

#define BDIM    512                   // 8 waves; TWO batches fused per block
#define NROWS   32
#define CDIM    1024
#define NSTEPS  31
#define BATCH   512

// TWO batches per 512-thread block, fused at INSTRUCTION level: every wave
// holds both batches' rows (R[2][4][16], 128 VGPR) and each phase runs both
// batches' independent instruction streams back-to-back (h fully unrolled,
// all register indices compile-time). Batch-0's dependent-chain stalls
// (shuffle butterflies, fma chains) are filled by batch-1's instructions
// WITHIN the same wave; each barrier serves two batch-steps (1.5
// barriers/batch-step). Grid 256 -> 1 block/CU; ILP replaces occupancy.
//
// Per batch: wave w owns banks k=0..3 = slots w+8k (strided, balanced
// init); lane holds elements [lane*16..+15]; bank->slot map in REGISTERS.
// Merged row overwrites slot sb's bank and D-row; the OTHER dead slot is
// idx[a] normally but idx[0] when a==1 (reference quirk).
//
// Argmin in POSITION space via static 496-pair triangle table (one pair
// per thread, filter j<n). Key u64 = (float_bits(d2)<<10)|(i*n+j): float
// bits order-monotone for d2>=0 => u64 min == reference (d2,flat) order.
// ALL distance math fp32 (validated: margins >> fp32 noise; absmax
// bit-identical across the fp64->fp32 switch). conv partials float4-packed
// lane-aligned. 3 barriers/step (serving 2 batches). No global reads after init.
__device__ __forceinline__ float reduce4f(float a0, float a1, float a2, float a3, int lane) {
    // Joint wave-sum of 4 fp32 values; lane l ends holding S_{l&3}.
    float t, r, b01, b23, c;
    t = (lane & 1) ? a0 : a1; r = (lane & 1) ? a1 : a0; b01 = r + __shfl_xor(t, 1);
    t = (lane & 1) ? a2 : a3; r = (lane & 1) ? a3 : a2; b23 = r + __shfl_xor(t, 1);
    t = (lane & 2) ? b01 : b23; r = (lane & 2) ? b23 : b01; c = r + __shfl_xor(t, 2);
    c += __shfl_xor(c, 4); c += __shfl_xor(c, 8); c += __shfl_xor(c, 16); c += __shfl_xor(c, 32);
    return c;
}

__global__ __launch_bounds__(BDIM, 2)
void merge_tree_kernel(const float* __restrict__ xin,  // B*32*1024 fp32
                       const float* __restrict__ wz,   // 6 fp32 (1,2,3)
                       const float* __restrict__ bz,   // 1 fp32
                       float* __restrict__ out)        // B*1024 fp32
{
    const int b0   = blockIdx.x * 2;  // this block's two batches
    const int tid  = threadIdx.x;
    const int lane = tid & 63;
    const int wid  = tid >> 6;        // 0..7

    __shared__ float  D[2][NROWS][NROWS + 1];   // slot-indexed d2 per batch
    __shared__ float4 mA4[2][4 * 64];           // conv partial (ch0)
    __shared__ float4 mB4[2][4 * 64];           // conv partial (ch1)
    __shared__ int    idxbuf[2][2][NROWS];      // [h][p][pos] -> slot
    __shared__ int    pairTab[496];             // static triangle (i<<8)|j
    __shared__ unsigned long long wp[2][8];     // per-wave argmin partials

    const float w00 = wz[0], w01 = wz[1], w02 = wz[2];
    const float w10 = wz[3], w11 = wz[4], w12 = wz[5];
    const float cb  = bz[0];

    float R[2][4][16];                // both batches' rows (128 VGPR)
    float m[2][16];                   // merged rows
    int   bs[2][4];                   // bank -> slot, -1 dead (registers)
    #pragma unroll
    for (int h = 0; h < 2; h++)
        #pragma unroll
        for (int k = 0; k < 4; k++) bs[h][k] = wid + (k << 3);

    if (tid < NROWS) {
        idxbuf[0][0][tid] = tid;
        idxbuf[1][0][tid] = tid;
        int i = tid;
        int base = 31 * i - (i * (i - 1)) / 2;
        for (int j = i + 1; j < NROWS; j++)
            pairTab[base + (j - i - 1)] = (i << 8) | j;
    }

    // ---------- init: per batch (sequential), single-pass stream + capture ----------
    #pragma unroll
    for (int h = 0; h < 2; h++) {
        const float* xb = xin + (size_t)(b0 + h) * NROWS * CDIM;
        float mm[16], nxt[16];
        {
            const float4* src = (const float4*)xb;    // row 0
            #pragma unroll
            for (int q = 0; q < 4; q++) {
                float4 t = src[lane * 4 + q];
                mm[4*q] = t.x; mm[4*q+1] = t.y; mm[4*q+2] = t.z; mm[4*q+3] = t.w;
            }
        }
        #pragma unroll 1
        for (int i = 0; i < NROWS; i++) {
            if (i < NROWS - 1) {                      // prefetch row i+1
                const float4* src = (const float4*)(xb + (size_t)(i + 1) * CDIM);
                #pragma unroll
                for (int q = 0; q < 4; q++) {
                    float4 t = src[lane * 4 + q];
                    nxt[4*q] = t.x; nxt[4*q+1] = t.y; nxt[4*q+2] = t.z; nxt[4*q+3] = t.w;
                }
            }
            float accv[4];
            #pragma unroll
            for (int k = 0; k < 4; k++) {
                const int s = wid + (k << 3);         // strided slot, wave-uniform
                float acc0 = 0.0f, acc1 = 0.0f;
                if (s < i) {                          // wave-uniform
                    #pragma unroll
                    for (int e = 0; e < 8; e++) {
                        float d0 = mm[e] - R[h][k][e];
                        float d1 = mm[e + 8] - R[h][k][e + 8];
                        acc0 += d0 * d0;
                        acc1 += d1 * d1;
                    }
                } else if (s == i) {                  // owner captures streamed row
                    #pragma unroll
                    for (int e = 0; e < 16; e++) R[h][k][e] = mm[e];
                }
                accv[k] = acc0 + acc1;
            }
            float c = reduce4f(accv[0], accv[1], accv[2], accv[3], lane);
            int s_lane = wid + ((lane & 3) << 3);
            if (lane < 4 && s_lane < i) { D[h][i][s_lane] = c; D[h][s_lane][i] = c; }

            if (i < NROWS - 1) {
                #pragma unroll
                for (int e = 0; e < 16; e++) mm[e] = nxt[e];
            }
        }
    }
    __syncthreads();

    // ---------- main merge loop: 3 barriers/step serve BOTH batches ----------
    int p = 0;
    #pragma unroll 1
    for (int step = 0; step < NSTEPS; step++) {
        const int n = NROWS - step;
        const uint32_t M = 0xFFFFFFFFu / (uint32_t)n + 1u;  // exact for flat<2^27

        // --- argmin scan: one pair per thread, both batches (independent) ---
        unsigned long long bk0 = ~0ull, bk1 = ~0ull;
        if (tid < 496) {
            const int pr = pairTab[tid];
            const int i2 = pr >> 8, j2 = pr & 255;          // i2 < j2 < 32
            if (j2 < n) {
                const int si0 = idxbuf[0][p][i2], sj0 = idxbuf[0][p][j2];
                const int si1 = idxbuf[1][p][i2], sj1 = idxbuf[1][p][j2];
                const unsigned fl = (unsigned)(i2 * n + j2);
                uint32_t d0 = __float_as_uint(D[0][si0][sj0]);
                uint32_t d1 = __float_as_uint(D[1][si1][sj1]);
                bk0 = ((unsigned long long)d0 << 10) | fl;
                bk1 = ((unsigned long long)d1 << 10) | fl;
            }
        }
        #pragma unroll
        for (int off = 1; off < 64; off <<= 1) {            // two interleaved butterflies
            unsigned long long o0 = __shfl_xor(bk0, off);
            unsigned long long o1 = __shfl_xor(bk1, off);
            bk0 = (o0 < bk0) ? o0 : bk0;
            bk1 = (o1 < bk1) ? o1 : bk1;
        }
        if (lane == 0) { wp[0][wid] = bk0; wp[1][wid] = bk1; }
        __syncthreads();                                   // B1

        // --- final reduce + conv + bookkeeping, per batch (unrolled) ---
        int a_[2], bbj_[2], sa_[2], sb_[2], dead_[2];
        #pragma unroll
        for (int h = 0; h < 2; h++) {
            unsigned long long bk = wp[h][0];
            #pragma unroll
            for (int w = 1; w < 8; w++) {
                unsigned long long ov = wp[h][w];
                bk = (ov < bk) ? ov : bk;
            }
            const int bp = (int)(bk & 1023u);
            a_[h]   = (int)__umulhi((uint32_t)bp, M);
            bbj_[h] = bp - a_[h] * n;
            sa_[h]  = idxbuf[h][p][a_[h]];
            sb_[h]  = idxbuf[h][p][bbj_[h]];
            dead_[h] = (a_[h] == 1) ? idxbuf[h][p][0] : sa_[h];
        }
        #pragma unroll
        for (int h = 0; h < 2; h++) {
            #pragma unroll
            for (int k = 0; k < 4; k++) {
                const int s = bs[h][k];                    // register, wave-uniform
                if (s == sa_[h] || s == sb_[h]) {
                    float hl = __shfl_up(R[h][k][15], 1);  if (lane == 0)  hl = 0.0f;
                    float hr = __shfl_down(R[h][k][0], 1); if (lane == 63) hr = 0.0f;
                    float4* dst = (s == sa_[h]) ? mA4[h] : mB4[h];
                    const float c0 = (s == sa_[h]) ? w00 : w10;
                    const float c1 = (s == sa_[h]) ? w01 : w11;
                    const float c2 = (s == sa_[h]) ? w02 : w12;
                    #pragma unroll
                    for (int q = 0; q < 4; q++) {
                        float vv[4];
                        #pragma unroll
                        for (int j = 0; j < 4; j++) {
                            const int e = 4 * q + j;
                            float xm1 = (e == 0)  ? hl : R[h][k][e - 1];
                            float xp1 = (e == 15) ? hr : R[h][k][e + 1];
                            vv[j] = c0 * xm1 + c1 * R[h][k][e] + c2 * xp1;
                        }
                        dst[q * 64 + lane] = make_float4(vv[0], vv[1], vv[2], vv[3]);
                    }
                }
            }
            // bookkeeping (merged keeps slot id sb)
            if (tid == 0) idxbuf[h][p ^ 1][0] = sb_[h];
            if (tid >= 1 && tid < n - 1) {
                int kk = tid + 1;
                int src = (kk == bbj_[h]) ? 1 : ((kk == a_[h]) ? 0 : kk);
                idxbuf[h][p ^ 1][tid] = idxbuf[h][p][src];
            }
        }
        __syncthreads();                                   // B2

        // --- finalize m + dist + D-writes, per batch (unrolled, interleavable) ---
        #pragma unroll
        for (int h = 0; h < 2; h++) {
            #pragma unroll
            for (int q = 0; q < 4; q++) {
                float4 va = mA4[h][q * 64 + lane];
                float4 vb = mB4[h][q * 64 + lane];
                float v0 = cb + va.x + vb.x;
                float v1 = cb + va.y + vb.y;
                float v2 = cb + va.z + vb.z;
                float v3 = cb + va.w + vb.w;
                m[h][4*q+0] = v0 > 0.0f ? v0 : 0.0f;
                m[h][4*q+1] = v1 > 0.0f ? v1 : 0.0f;
                m[h][4*q+2] = v2 > 0.0f ? v2 : 0.0f;
                m[h][4*q+3] = v3 > 0.0f ? v3 : 0.0f;
            }
            float accv[4]; int slv[4];
            #pragma unroll
            for (int k = 0; k < 4; k++) {
                int s = bs[h][k];
                if (s == sb_[h]) {                         // wave-uniform
                    #pragma unroll
                    for (int e = 0; e < 16; e++) R[h][k][e] = m[h][e];
                }
                if (s == dead_[h]) {                       // wave-uniform
                    bs[h][k] = -1;
                    s = -1;
                }
                const int live = (s >= 0 && s != sb_[h]) ? s : -1;
                slv[k] = live;
                float acc0 = 0.0f, acc1 = 0.0f;
                if (live >= 0) {                           // wave-uniform
                    #pragma unroll
                    for (int e = 0; e < 8; e++) {
                        float d0 = m[h][e] - R[h][k][e];
                        float d1 = m[h][e + 8] - R[h][k][e + 8];
                        acc0 += d0 * d0;
                        acc1 += d1 * d1;
                    }
                }
                accv[k] = acc0 + acc1;
            }
            float c = reduce4f(accv[0], accv[1], accv[2], accv[3], lane);
            int s_lane = slv[0];
            s_lane = ((lane & 3) == 1) ? slv[1] : s_lane;
            s_lane = ((lane & 3) == 2) ? slv[2] : s_lane;
            s_lane = ((lane & 3) == 3) ? slv[3] : s_lane;
            if (lane < 4 && s_lane >= 0) {
                D[h][sb_[h]][s_lane] = c; D[h][s_lane][sb_[h]] = c;
            }
        }
        __syncthreads();                                   // B3
        p ^= 1;
    }

    // final merged rows: wave h writes batch b0+h
    #pragma unroll
    for (int h = 0; h < 2; h++) {
        if (wid == h) {
            float4* od = (float4*)(out + (size_t)(b0 + h) * CDIM);
            #pragma unroll
            for (int q = 0; q < 4; q++)
                od[lane * 4 + q] = make_float4(m[h][4*q], m[h][4*q+1], m[h][4*q+2], m[h][4*q+3]);
        }
    }
}

extern "C" void kernel_launch(void* const* d_in, const int* in_sizes, int n_in,
                              void* d_out, int out_size, void* d_ws, size_t ws_size,
                              hipStream_t stream) {
    const float* x  = (const float*)d_in[0]; // fp32 (512,32,1024)
    const float* w  = (const float*)d_in[1]; // fp32 (1,2,3)
    const float* cb = (const float*)d_in[2]; // fp32 (1,)
    float* out = (float*)d_out;              // fp32 (512,1024)
    (void)d_ws; (void)ws_size; (void)in_sizes; (void)n_in; (void)out_size;

    hipLaunchKernelGGL(merge_tree_kernel, dim3(BATCH / 2), dim3(BDIM), 0, stream,
                       x, w, cb, out);
}

// Round 12
// 216.229 us; speedup vs baseline: 1.2753x; 1.2753x over previous
//
#include <hip/hip_runtime.h>
#include <stdint.h>

#define BDIM    512                   // 8 waves per batch
#define NROWS   32
#define CDIM    1024
#define NSTEPS  31
#define BATCH   512

// One 512-thread block (8 waves) per batch. ALL alive rows live in REGISTERS:
// wave w owns 4 "banks" k=0..3 holding slots s = w + 8k (strided ownership,
// balanced init); lane holds elements [lane*16..+15]; bank->slot map bs[4]
// in REGISTERS. Merged row overwrites slot sb's bank and D-row. The OTHER
// dead slot is idx[a] normally but idx[0] when a==1 (reference quirk).
//
// 2 BARRIERS/STEP. The argmin candidate set is split:
//  - OLD pairs (both positions >= 1): static 465-pair triangle table
//    (1<=i<j<32, filter j<n) -> D[idx[i]][idx[j]] -> per-wave partials
//    wp[0..7]. Excluding position 0 is FREE (baked into the table).
//  - FRESH pairs (0, j'): phase B's lanes 0-3 hold the merged-row
//    distances in registers; key (bits(c)<<10)|j' (j' = npos[s_lane];
//    flat' = 0*n'+j' < any old flat => exact reference tie order),
//    2-shuffle mini-reduce -> wp[8+wid]. Seeded for step 0 from D row 0.
// Decode reduces 16 partials. B3 is removed: phase B writes only
// D[sb][*]/[*][sb]; the next scan (i,j>=1) never reads slot sb's row/col
// (sb = next position 0) -> disjoint addresses; all other cross-wave
// dataflows (mA4/mB4, idx, npos, wp) cross >= 1 barrier.
//
// ALL distance math fp32 (validated: margins >> fp32 noise; absmax
// bit-identical across the fp64->fp32 switch). Argmin key u64 =
// (float_bits(d2)<<10)|flat — order-monotone for d2>=0 => u64 min ==
// reference (d2, flat) lexicographic order. conv partials float4-packed,
// lane-aligned (4x ds_read_b128 per array). No global reads after init.
__device__ __forceinline__ float reduce4f(float a0, float a1, float a2, float a3, int lane) {
    // Joint wave-sum of 4 fp32 values; lane l ends holding S_{l&3}.
    float t, r, b01, b23, c;
    t = (lane & 1) ? a0 : a1; r = (lane & 1) ? a1 : a0; b01 = r + __shfl_xor(t, 1);
    t = (lane & 1) ? a2 : a3; r = (lane & 1) ? a3 : a2; b23 = r + __shfl_xor(t, 1);
    t = (lane & 2) ? b01 : b23; r = (lane & 2) ? b23 : b01; c = r + __shfl_xor(t, 2);
    c += __shfl_xor(c, 4); c += __shfl_xor(c, 8); c += __shfl_xor(c, 16); c += __shfl_xor(c, 32);
    return c;
}

__global__ __launch_bounds__(BDIM, 4)
void merge_tree_kernel(const float* __restrict__ xin,  // B*32*1024 fp32
                       const float* __restrict__ wz,   // 6 fp32 (1,2,3)
                       const float* __restrict__ bz,   // 1 fp32
                       float* __restrict__ out)        // B*1024 fp32
{
    const int b    = blockIdx.x;
    const int tid  = threadIdx.x;
    const int lane = tid & 63;
    const int wid  = tid >> 6;        // 0..7

    const float* xb = xin + (size_t)b * NROWS * CDIM;

    __shared__ float  D[NROWS][NROWS + 1];   // slot-indexed d2, fp32, padded
    __shared__ float4 mA4[4 * 64];           // conv partial (ch0), [q][lane] float4
    __shared__ float4 mB4[4 * 64];           // conv partial (ch1), [q][lane] float4
    __shared__ int    idxbuf[2][NROWS];      // logical pos -> slot (dbl-buffered)
    __shared__ int    npos[NROWS];           // slot -> NEXT-step pos (survivors)
    __shared__ int    pairTab[465];          // static triangle (i<<8)|j, 1<=i<j<32
    __shared__ unsigned long long wp[16];    // [0..7] scan, [8..15] fresh partials

    const float w00 = wz[0], w01 = wz[1], w02 = wz[2];
    const float w10 = wz[3], w11 = wz[4], w12 = wz[5];
    const float cb  = bz[0];

    float R[4][16];                   // 4 owned rows (64 VGPRs)
    float m[16];                      // streamed / merged row
    float nxt[16];                    // init prefetch buffer
    int   bs[4];                      // bank -> slot (own wave only), -1 dead
    #pragma unroll
    for (int k = 0; k < 4; k++) bs[k] = wid + (k << 3);   // strided ownership

    if (tid < NROWS) {
        idxbuf[0][tid] = tid;
        // triangle table rows i=1..30: base(i) = 31(i-1) - i(i-1)/2
        int i = tid;
        if (i >= 1 && i < 31) {
            int base = 31 * (i - 1) - (i * (i - 1)) / 2;
            for (int j = i + 1; j < NROWS; j++)
                pairTab[base + (j - i - 1)] = (i << 8) | j;
        }
    }
    if (tid < 16) wp[tid] = ~0ull;    // wp[8..15] empty except step-0 seed

    // ---------- single-pass init: stream row i, owner captures, dist vs s<i ----------
    {
        const float4* src = (const float4*)xb;    // row 0
        #pragma unroll
        for (int q = 0; q < 4; q++) {
            float4 t = src[lane * 4 + q];
            m[4*q] = t.x; m[4*q+1] = t.y; m[4*q+2] = t.z; m[4*q+3] = t.w;
        }
    }
    #pragma unroll 1
    for (int i = 0; i < NROWS; i++) {
        if (i < NROWS - 1) {                      // prefetch row i+1
            const float4* src = (const float4*)(xb + (size_t)(i + 1) * CDIM);
            #pragma unroll
            for (int q = 0; q < 4; q++) {
                float4 t = src[lane * 4 + q];
                nxt[4*q] = t.x; nxt[4*q+1] = t.y; nxt[4*q+2] = t.z; nxt[4*q+3] = t.w;
            }
        }
        float accv[4];
        #pragma unroll
        for (int k = 0; k < 4; k++) {
            const int s = wid + (k << 3);         // strided slot, wave-uniform
            float acc0 = 0.0f, acc1 = 0.0f;
            if (s < i) {                          // wave-uniform
                #pragma unroll
                for (int e = 0; e < 8; e++) {
                    float d0 = m[e] - R[k][e];
                    float d1 = m[e + 8] - R[k][e + 8];
                    acc0 += d0 * d0;
                    acc1 += d1 * d1;
                }
            } else if (s == i) {                  // owner captures streamed row
                #pragma unroll
                for (int e = 0; e < 16; e++) R[k][e] = m[e];
            }
            accv[k] = acc0 + acc1;
        }
        float c = reduce4f(accv[0], accv[1], accv[2], accv[3], lane);
        int s_lane = wid + ((lane & 3) << 3);     // slot for this lane's sum
        if (lane < 4 && s_lane < i) { D[i][s_lane] = c; D[s_lane][i] = c; }

        if (i < NROWS - 1) {
            #pragma unroll
            for (int e = 0; e < 16; e++) m[e] = nxt[e];
        }
    }
    __syncthreads();

    // ---------- seed wp[8]: row-0 pairs (0,j) j=1..31, flat = j (n=32) ----------
    if (wid == 0) {
        unsigned long long sk = ~0ull;
        if (lane < 31) {
            uint32_t d2b = __float_as_uint(D[0][lane + 1]);
            sk = ((unsigned long long)d2b << 10) | (unsigned)(lane + 1);
        }
        #pragma unroll
        for (int off = 1; off < 64; off <<= 1) {
            unsigned long long ov = __shfl_xor(sk, off);
            sk = (ov < sk) ? ov : sk;
        }
        if (lane == 0) wp[8] = sk;
        // wp[8] written before this wave reaches B1 of step 0 -> visible at decode
    }

    // ---------- main merge loop: 2 barriers/step ----------
    int p = 0;
    #pragma unroll 1
    for (int step = 0; step < NSTEPS; step++) {
        const int n = NROWS - step;
        int* idx  = idxbuf[p];
        int* nidx = idxbuf[p ^ 1];
        const uint32_t M = 0xFFFFFFFFu / (uint32_t)n + 1u;  // exact for flat<2^27

        // --- scan OLD pairs (positions >= 1): one static pair per thread ---
        unsigned long long bk = ~0ull;
        if (tid < 465) {
            const int pr = pairTab[tid];
            const int i2 = pr >> 8, j2 = pr & 255;          // 1 <= i2 < j2 < 32
            if (j2 < n) {                                   // both alive
                const int si = idx[i2], sj = idx[j2];
                uint32_t d2b = __float_as_uint(D[si][sj]);  // d2>=0: monotone bits
                bk = ((unsigned long long)d2b << 10) | (unsigned)(i2 * n + j2);
            }
        }
        #pragma unroll
        for (int off = 1; off < 64; off <<= 1) {
            unsigned long long ov = __shfl_xor(bk, off);
            bk = (ov < bk) ? ov : bk;
        }
        if (lane == 0) wp[wid] = bk;
        __syncthreads();                                   // B1

        // --- final reduce of 16 partials (8 scan + 8 fresh), uniform ---
        bk = wp[0];
        #pragma unroll
        for (int w = 1; w < 16; w++) {
            unsigned long long ov = wp[w];
            bk = (ov < bk) ? ov : bk;
        }
        const int bp  = (int)(bk & 1023u);
        const int a   = (int)__umulhi((uint32_t)bp, M);
        const int bbj = bp - a * n;
        const int sa  = idx[a], sb = idx[bbj];
        const int deadSlot = (a == 1) ? idx[0] : sa;

        // --- conv partials by owner waves, from registers, float4-packed LDS ---
        #pragma unroll
        for (int k = 0; k < 4; k++) {
            const int s = bs[k];                           // register, wave-uniform
            if (s == sa || s == sb) {
                float hl = __shfl_up(R[k][15], 1);  if (lane == 0)  hl = 0.0f;
                float hr = __shfl_down(R[k][0], 1); if (lane == 63) hr = 0.0f;
                float4* dst = (s == sa) ? mA4 : mB4;
                const float c0 = (s == sa) ? w00 : w10;
                const float c1 = (s == sa) ? w01 : w11;
                const float c2 = (s == sa) ? w02 : w12;
                #pragma unroll
                for (int q = 0; q < 4; q++) {
                    float vv[4];
                    #pragma unroll
                    for (int j = 0; j < 4; j++) {
                        const int e = 4 * q + j;
                        float xm1 = (e == 0)  ? hl : R[k][e - 1];
                        float xp1 = (e == 15) ? hr : R[k][e + 1];
                        vv[j] = c0 * xm1 + c1 * R[k][e] + c2 * xp1;
                    }
                    dst[q * 64 + lane] = make_float4(vv[0], vv[1], vv[2], vv[3]);
                }
            }
        }
        // --- bookkeeping: next order + slot->next-pos scatter (free npos) ---
        if (tid == 0) { nidx[0] = sb; npos[sb] = 0; }
        if (tid >= 1 && tid < n - 1) {
            int kk = tid + 1;
            int src = (kk == bbj) ? 1 : ((kk == a) ? 0 : kk);
            int sl2 = idx[src];
            nidx[tid] = sl2;
            npos[sl2] = tid;                               // survivors distinct; no race
        }
        __syncthreads();                                   // B2

        // --- finalize m: 4x ds_read_b128 per array, conflict-free ---
        #pragma unroll
        for (int q = 0; q < 4; q++) {
            float4 va = mA4[q * 64 + lane];
            float4 vb = mB4[q * 64 + lane];
            float v0 = cb + va.x + vb.x;
            float v1 = cb + va.y + vb.y;
            float v2 = cb + va.z + vb.z;
            float v3 = cb + va.w + vb.w;
            m[4*q+0] = v0 > 0.0f ? v0 : 0.0f;
            m[4*q+1] = v1 > 0.0f ? v1 : 0.0f;
            m[4*q+2] = v2 > 0.0f ? v2 : 0.0f;
            m[4*q+3] = v3 > 0.0f ? v3 : 0.0f;
        }
        // owner(sb): bank <- m; owner(deadSlot): kill bank; dists vs live banks
        float accv[4]; int slv[4];
        #pragma unroll
        for (int k = 0; k < 4; k++) {
            int s = bs[k];
            if (s == sb) {                                 // wave-uniform
                #pragma unroll
                for (int e = 0; e < 16; e++) R[k][e] = m[e];
            }
            if (s == deadSlot) {                           // wave-uniform
                bs[k] = -1;
                s = -1;
            }
            const int live = (s >= 0 && s != sb) ? s : -1;
            slv[k] = live;
            float acc0 = 0.0f, acc1 = 0.0f;
            if (live >= 0) {                               // wave-uniform
                #pragma unroll
                for (int e = 0; e < 8; e++) {
                    float d0 = m[e] - R[k][e];
                    float d1 = m[e + 8] - R[k][e + 8];
                    acc0 += d0 * d0;
                    acc1 += d1 * d1;
                }
            }
            accv[k] = acc0 + acc1;
        }
        // joint reduce: lane l holds sum for bank (l&3)
        float c = reduce4f(accv[0], accv[1], accv[2], accv[3], lane);
        int s_lane = slv[0];
        s_lane = ((lane & 3) == 1) ? slv[1] : s_lane;
        s_lane = ((lane & 3) == 2) ? slv[2] : s_lane;
        s_lane = ((lane & 3) == 3) ? slv[3] : s_lane;
        // write D (future steps) + fresh-pair side channel (next step argmin)
        unsigned long long nk = ~0ull;
        if (lane < 4 && s_lane >= 0) {
            D[sb][s_lane] = c; D[s_lane][sb] = c;
            const int fl = npos[s_lane];                   // partner next-step pos >= 1
            nk = ((unsigned long long)__float_as_uint(c) << 10) | (unsigned)fl;
        }
        {   // mini-reduce over lanes 0..3 (closed under xor 1,2)
            unsigned long long ov = __shfl_xor(nk, 1); nk = (ov < nk) ? ov : nk;
            ov = __shfl_xor(nk, 2);                    nk = (ov < nk) ? ov : nk;
        }
        if (lane == 0) wp[8 + wid] = nk;
        p ^= 1;
        // NO third barrier: next scan touches only positions >= 1 (slots != sb)
        // -> disjoint from this phase's D[sb][*]/[*][sb] writes; wp[8..15]
        // reads happen after next step's B1.
    }

    // final merged row is in m (all waves); wave 0 writes it
    if (wid == 0) {
        float4* od = (float4*)(out + (size_t)b * CDIM);
        #pragma unroll
        for (int q = 0; q < 4; q++)
            od[lane * 4 + q] = make_float4(m[4*q], m[4*q+1], m[4*q+2], m[4*q+3]);
    }
}

extern "C" void kernel_launch(void* const* d_in, const int* in_sizes, int n_in,
                              void* d_out, int out_size, void* d_ws, size_t ws_size,
                              hipStream_t stream) {
    const float* x  = (const float*)d_in[0]; // fp32 (512,32,1024)
    const float* w  = (const float*)d_in[1]; // fp32 (1,2,3)
    const float* cb = (const float*)d_in[2]; // fp32 (1,)
    float* out = (float*)d_out;              // fp32 (512,1024)
    (void)d_ws; (void)ws_size; (void)in_sizes; (void)n_in; (void)out_size;

    hipLaunchKernelGGL(merge_tree_kernel, dim3(BATCH), dim3(BDIM), 0, stream,
                       x, w, cb, out);
}

// Round 13
// 204.273 us; speedup vs baseline: 1.3500x; 1.0585x over previous
//
#include <hip/hip_runtime.h>
#include <stdint.h>

#define BDIM    512                   // 8 waves per batch
#define NROWS   32
#define CDIM    1024
#define NSTEPS  31
#define BATCH   512

// One 512-thread block (8 waves) per batch. ALL alive rows live in REGISTERS:
// wave w owns 4 "banks" k=0..3 holding slots s = w + 8k (strided ownership,
// balanced init); lane holds elements [lane*16..+15]. Bank->slot map bs[4]
// lives in REGISTERS (only the owning wave ever reads it). Merged row
// overwrites slot sb's bank and D-row. The OTHER dead slot is idx[a]
// normally but idx[0] when a==1 (reference quirk) — kill THAT bank.
//
// Argmin scan in POSITION space via a STATIC 496-entry triangle table
// (pairs i<j<32, filter j<n): exactly one pair per thread, no loop, no
// pos[] array at all. Key u64 = (float_bits(d2)<<10) | (i*n+j) — float
// bits order-monotone for d2>=0; u64 min == reference (d2, flat) order.
// ALL distance math fp32 (validated: decisions identical, margins >> fp32
// noise; absmax bit-identical across fp64->fp32 switch).
// conv partials float4-packed, lane-aligned (4x ds_read_b128 per array).
// 3 barriers/step — proven minimal: both 2-barrier designs (R6 side
// channel, R12 static-exclusion side channel) regressed; the replacement
// work on the serial chain costs more than the barrier drain.
// No global reads after init.
__device__ __forceinline__ float reduce4f(float a0, float a1, float a2, float a3, int lane) {
    // Joint wave-sum of 4 fp32 values; lane l ends holding S_{l&3}.
    float t, r, b01, b23, c;
    t = (lane & 1) ? a0 : a1; r = (lane & 1) ? a1 : a0; b01 = r + __shfl_xor(t, 1);
    t = (lane & 1) ? a2 : a3; r = (lane & 1) ? a3 : a2; b23 = r + __shfl_xor(t, 1);
    t = (lane & 2) ? b01 : b23; r = (lane & 2) ? b23 : b01; c = r + __shfl_xor(t, 2);
    c += __shfl_xor(c, 4); c += __shfl_xor(c, 8); c += __shfl_xor(c, 16); c += __shfl_xor(c, 32);
    return c;
}

__global__ __launch_bounds__(BDIM, 4)
void merge_tree_kernel(const float* __restrict__ xin,  // B*32*1024 fp32
                       const float* __restrict__ wz,   // 6 fp32 (1,2,3)
                       const float* __restrict__ bz,   // 1 fp32
                       float* __restrict__ out)        // B*1024 fp32
{
    const int b    = blockIdx.x;
    const int tid  = threadIdx.x;
    const int lane = tid & 63;
    const int wid  = tid >> 6;        // 0..7

    const float* xb = xin + (size_t)b * NROWS * CDIM;

    __shared__ float  D[NROWS][NROWS + 1];   // slot-indexed d2, fp32, padded
    __shared__ float4 mA4[4 * 64];           // conv partial (ch0), [q][lane] float4
    __shared__ float4 mB4[4 * 64];           // conv partial (ch1), [q][lane] float4
    __shared__ int    idxbuf[2][NROWS];      // logical pos -> slot (dbl-buffered)
    __shared__ int    pairTab[496];          // static triangle (i<<8)|j, i<j<32
    __shared__ unsigned long long wp[8];     // per-wave argmin partial key

    const float w00 = wz[0], w01 = wz[1], w02 = wz[2];
    const float w10 = wz[3], w11 = wz[4], w12 = wz[5];
    const float cb  = bz[0];

    float R[4][16];                   // 4 owned rows (64 VGPRs)
    float m[16];                      // streamed / merged row
    float nxt[16];                    // init prefetch buffer
    int   bs[4];                      // bank -> slot (own wave only), -1 dead
    #pragma unroll
    for (int k = 0; k < 4; k++) bs[k] = wid + (k << 3);   // strided ownership

    if (tid < NROWS) {
        idxbuf[0][tid] = tid;
        // build static triangle table: row i entries at 31i - i(i-1)/2
        int i = tid;
        int base = 31 * i - (i * (i - 1)) / 2;
        for (int j = i + 1; j < NROWS; j++)
            pairTab[base + (j - i - 1)] = (i << 8) | j;
    }

    // ---------- single-pass init: stream row i, owner captures, dist vs s<i ----------
    {
        const float4* src = (const float4*)xb;    // row 0
        #pragma unroll
        for (int q = 0; q < 4; q++) {
            float4 t = src[lane * 4 + q];
            m[4*q] = t.x; m[4*q+1] = t.y; m[4*q+2] = t.z; m[4*q+3] = t.w;
        }
    }
    #pragma unroll 1
    for (int i = 0; i < NROWS; i++) {
        if (i < NROWS - 1) {                      // prefetch row i+1
            const float4* src = (const float4*)(xb + (size_t)(i + 1) * CDIM);
            #pragma unroll
            for (int q = 0; q < 4; q++) {
                float4 t = src[lane * 4 + q];
                nxt[4*q] = t.x; nxt[4*q+1] = t.y; nxt[4*q+2] = t.z; nxt[4*q+3] = t.w;
            }
        }
        float accv[4];
        #pragma unroll
        for (int k = 0; k < 4; k++) {
            const int s = wid + (k << 3);         // strided slot, wave-uniform
            float acc0 = 0.0f, acc1 = 0.0f;
            if (s < i) {                          // wave-uniform
                #pragma unroll
                for (int e = 0; e < 8; e++) {
                    float d0 = m[e] - R[k][e];
                    float d1 = m[e + 8] - R[k][e + 8];
                    acc0 += d0 * d0;
                    acc1 += d1 * d1;
                }
            } else if (s == i) {                  // owner captures streamed row
                #pragma unroll
                for (int e = 0; e < 16; e++) R[k][e] = m[e];
            }
            accv[k] = acc0 + acc1;
        }
        float c = reduce4f(accv[0], accv[1], accv[2], accv[3], lane);
        int s_lane = wid + ((lane & 3) << 3);     // slot for this lane's sum
        if (lane < 4 && s_lane < i) { D[i][s_lane] = c; D[s_lane][i] = c; }

        if (i < NROWS - 1) {
            #pragma unroll
            for (int e = 0; e < 16; e++) m[e] = nxt[e];
        }
    }
    __syncthreads();

    // ---------- main merge loop: 3 barriers/step ----------
    int p = 0;
    #pragma unroll 1
    for (int step = 0; step < NSTEPS; step++) {
        const int n = NROWS - step;
        int* idx  = idxbuf[p];
        int* nidx = idxbuf[p ^ 1];
        const uint32_t M = 0xFFFFFFFFu / (uint32_t)n + 1u;  // exact for flat<2^27

        // --- argmin: one live-position pair per thread (static table) ---
        unsigned long long bk = ~0ull;
        if (tid < 496) {
            const int pr = pairTab[tid];
            const int i2 = pr >> 8, j2 = pr & 255;          // i2 < j2 < 32
            if (j2 < n) {                                   // both alive
                const int si = idx[i2], sj = idx[j2];
                uint32_t d2b = __float_as_uint(D[si][sj]);  // d2>=0: monotone bits
                bk = ((unsigned long long)d2b << 10) | (unsigned)(i2 * n + j2);
            }
        }
        #pragma unroll
        for (int off = 1; off < 64; off <<= 1) {
            unsigned long long ov = __shfl_xor(bk, off);
            bk = (ov < bk) ? ov : bk;
        }
        if (lane == 0) wp[wid] = bk;
        __syncthreads();                                   // B1

        // --- final reduce of 8 partials, redundant on every thread (uniform) ---
        bk = wp[0];
        #pragma unroll
        for (int w = 1; w < 8; w++) {
            unsigned long long ov = wp[w];
            bk = (ov < bk) ? ov : bk;
        }
        const int bp  = (int)(bk & 1023u);
        const int a   = (int)__umulhi((uint32_t)bp, M);
        const int bbj = bp - a * n;
        const int sa  = idx[a], sb = idx[bbj];
        const int deadSlot = (a == 1) ? idx[0] : sa;

        // --- conv partials by owner waves, from registers, float4-packed LDS ---
        #pragma unroll
        for (int k = 0; k < 4; k++) {
            const int s = bs[k];                           // register, wave-uniform
            if (s == sa || s == sb) {
                float hl = __shfl_up(R[k][15], 1);  if (lane == 0)  hl = 0.0f;
                float hr = __shfl_down(R[k][0], 1); if (lane == 63) hr = 0.0f;
                float4* dst = (s == sa) ? mA4 : mB4;
                const float c0 = (s == sa) ? w00 : w10;
                const float c1 = (s == sa) ? w01 : w11;
                const float c2 = (s == sa) ? w02 : w12;
                #pragma unroll
                for (int q = 0; q < 4; q++) {
                    float vv[4];
                    #pragma unroll
                    for (int j = 0; j < 4; j++) {
                        const int e = 4 * q + j;
                        float xm1 = (e == 0)  ? hl : R[k][e - 1];
                        float xp1 = (e == 15) ? hr : R[k][e + 1];
                        vv[j] = c0 * xm1 + c1 * R[k][e] + c2 * xp1;
                    }
                    dst[q * 64 + lane] = make_float4(vv[0], vv[1], vv[2], vv[3]);
                }
            }
        }
        // --- bookkeeping: next logical order (merged keeps slot id sb) ---
        if (tid == 0) nidx[0] = sb;
        if (tid >= 1 && tid < n - 1) {
            int kk = tid + 1;
            int src = (kk == bbj) ? 1 : ((kk == a) ? 0 : kk);
            nidx[tid] = idx[src];
        }
        __syncthreads();                                   // B2

        // --- finalize m: 4x ds_read_b128 per array, conflict-free ---
        #pragma unroll
        for (int q = 0; q < 4; q++) {
            float4 va = mA4[q * 64 + lane];
            float4 vb = mB4[q * 64 + lane];
            float v0 = cb + va.x + vb.x;
            float v1 = cb + va.y + vb.y;
            float v2 = cb + va.z + vb.z;
            float v3 = cb + va.w + vb.w;
            m[4*q+0] = v0 > 0.0f ? v0 : 0.0f;
            m[4*q+1] = v1 > 0.0f ? v1 : 0.0f;
            m[4*q+2] = v2 > 0.0f ? v2 : 0.0f;
            m[4*q+3] = v3 > 0.0f ? v3 : 0.0f;
        }
        // owner(sb): bank <- m; owner(deadSlot): kill bank; dists vs live banks
        float accv[4]; int slv[4];
        #pragma unroll
        for (int k = 0; k < 4; k++) {
            int s = bs[k];
            if (s == sb) {                                 // wave-uniform
                #pragma unroll
                for (int e = 0; e < 16; e++) R[k][e] = m[e];
            }
            if (s == deadSlot) {                           // wave-uniform
                bs[k] = -1;
                s = -1;
            }
            const int live = (s >= 0 && s != sb) ? s : -1;
            slv[k] = live;
            float acc0 = 0.0f, acc1 = 0.0f;
            if (live >= 0) {                               // wave-uniform
                #pragma unroll
                for (int e = 0; e < 8; e++) {
                    float d0 = m[e] - R[k][e];
                    float d1 = m[e + 8] - R[k][e + 8];
                    acc0 += d0 * d0;
                    acc1 += d1 * d1;
                }
            }
            accv[k] = acc0 + acc1;
        }
        // joint reduce: lane l holds sum for bank (l&3)
        float c = reduce4f(accv[0], accv[1], accv[2], accv[3], lane);
        int s_lane = slv[0];
        s_lane = ((lane & 3) == 1) ? slv[1] : s_lane;
        s_lane = ((lane & 3) == 2) ? slv[2] : s_lane;
        s_lane = ((lane & 3) == 3) ? slv[3] : s_lane;
        if (lane < 4 && s_lane >= 0) {
            D[sb][s_lane] = c; D[s_lane][sb] = c;
        }
        __syncthreads();                                   // B3
        p ^= 1;
    }

    // final merged row is in m (all waves); wave 0 writes it
    if (wid == 0) {
        float4* od = (float4*)(out + (size_t)b * CDIM);
        #pragma unroll
        for (int q = 0; q < 4; q++)
            od[lane * 4 + q] = make_float4(m[4*q], m[4*q+1], m[4*q+2], m[4*q+3]);
    }
}

extern "C" void kernel_launch(void* const* d_in, const int* in_sizes, int n_in,
                              void* d_out, int out_size, void* d_ws, size_t ws_size,
                              hipStream_t stream) {
    const float* x  = (const float*)d_in[0]; // fp32 (512,32,1024)
    const float* w  = (const float*)d_in[1]; // fp32 (1,2,3)
    const float* cb = (const float*)d_in[2]; // fp32 (1,)
    float* out = (float*)d_out;              // fp32 (512,1024)
    (void)d_ws; (void)ws_size; (void)in_sizes; (void)n_in; (void)out_size;

    hipLaunchKernelGGL(merge_tree_kernel, dim3(BATCH), dim3(BDIM), 0, stream,
                       x, w, cb, out);
}

// Round 14
// 201.353 us; speedup vs baseline: 1.3696x; 1.0145x over previous
//
#include <hip/hip_runtime.h>
#include <stdint.h>

#define BDIM    512                   // 8 waves per batch
#define NROWS   32
#define CDIM    1024
#define NSTEPS  31
#define BATCH   512

// One 512-thread block (8 waves) per batch. ALL alive rows live in REGISTERS:
// wave w owns 4 "banks" k=0..3 holding slots s = w + 8k (strided ownership,
// balanced init); lane holds elements [lane*16..+15]. Bank->slot map bs[4]
// lives in REGISTERS. Merged row overwrites slot sb's bank and D-row. The
// OTHER dead slot is idx[a] normally but idx[0] when a==1 (reference quirk).
//
// Argmin scan in POSITION space via a STATIC 496-entry triangle table
// (pairs i<j<32, filter j<n): one pair per thread. Key u64 =
// (float_bits(d2)<<10) | (i*n+j) — order-monotone for d2>=0; u64 min ==
// reference (d2, flat) order. Per-wave butterfly, then lane 0 does LDS
// atomicMin into wmin[step&1] (8 staggered atomics, PRE-barrier = off the
// critical path); decode after B1 is a SINGLE broadcast load (replaces 8
// loads + 7 u64 cmp-selects on every thread's post-B1 chain). wmin is
// double-buffered; buffer (step&1) is reset by tid 0 in phase B (all
// decode reads done before B2; next atomics to it are at step+2, three
// barriers later — fully ordered).
//
// ALL distance math fp32 (validated: decisions identical, margins >> fp32
// noise; absmax bit-identical across fp64->fp32 switch). conv partials
// float4-packed, lane-aligned (4x ds_read_b128 per array). 3 barriers/step
// — proven minimal (R6/R12 2-barrier designs both regressed).
// No global reads after init.
__device__ __forceinline__ float reduce4f(float a0, float a1, float a2, float a3, int lane) {
    // Joint wave-sum of 4 fp32 values; lane l ends holding S_{l&3}.
    float t, r, b01, b23, c;
    t = (lane & 1) ? a0 : a1; r = (lane & 1) ? a1 : a0; b01 = r + __shfl_xor(t, 1);
    t = (lane & 1) ? a2 : a3; r = (lane & 1) ? a3 : a2; b23 = r + __shfl_xor(t, 1);
    t = (lane & 2) ? b01 : b23; r = (lane & 2) ? b23 : b01; c = r + __shfl_xor(t, 2);
    c += __shfl_xor(c, 4); c += __shfl_xor(c, 8); c += __shfl_xor(c, 16); c += __shfl_xor(c, 32);
    return c;
}

__global__ __launch_bounds__(BDIM, 4)
void merge_tree_kernel(const float* __restrict__ xin,  // B*32*1024 fp32
                       const float* __restrict__ wz,   // 6 fp32 (1,2,3)
                       const float* __restrict__ bz,   // 1 fp32
                       float* __restrict__ out)        // B*1024 fp32
{
    const int b    = blockIdx.x;
    const int tid  = threadIdx.x;
    const int lane = tid & 63;
    const int wid  = tid >> 6;        // 0..7

    const float* xb = xin + (size_t)b * NROWS * CDIM;

    __shared__ float  D[NROWS][NROWS + 1];   // slot-indexed d2, fp32, padded
    __shared__ float4 mA4[4 * 64];           // conv partial (ch0), [q][lane] float4
    __shared__ float4 mB4[4 * 64];           // conv partial (ch1), [q][lane] float4
    __shared__ int    idxbuf[2][NROWS];      // logical pos -> slot (dbl-buffered)
    __shared__ int    pairTab[496];          // static triangle (i<<8)|j, i<j<32
    __shared__ unsigned long long wmin[2];   // argmin accumulator (dbl-buffered)

    const float w00 = wz[0], w01 = wz[1], w02 = wz[2];
    const float w10 = wz[3], w11 = wz[4], w12 = wz[5];
    const float cb  = bz[0];

    float R[4][16];                   // 4 owned rows (64 VGPRs)
    float m[16];                      // streamed / merged row
    float nxt[16];                    // init prefetch buffer
    int   bs[4];                      // bank -> slot (own wave only), -1 dead
    #pragma unroll
    for (int k = 0; k < 4; k++) bs[k] = wid + (k << 3);   // strided ownership

    if (tid < NROWS) {
        idxbuf[0][tid] = tid;
        // build static triangle table: row i entries at 31i - i(i-1)/2
        int i = tid;
        int base = 31 * i - (i * (i - 1)) / 2;
        for (int j = i + 1; j < NROWS; j++)
            pairTab[base + (j - i - 1)] = (i << 8) | j;
    }
    if (tid < 2) wmin[tid] = ~0ull;

    // ---------- single-pass init: stream row i, owner captures, dist vs s<i ----------
    {
        const float4* src = (const float4*)xb;    // row 0
        #pragma unroll
        for (int q = 0; q < 4; q++) {
            float4 t = src[lane * 4 + q];
            m[4*q] = t.x; m[4*q+1] = t.y; m[4*q+2] = t.z; m[4*q+3] = t.w;
        }
    }
    #pragma unroll 1
    for (int i = 0; i < NROWS; i++) {
        if (i < NROWS - 1) {                      // prefetch row i+1
            const float4* src = (const float4*)(xb + (size_t)(i + 1) * CDIM);
            #pragma unroll
            for (int q = 0; q < 4; q++) {
                float4 t = src[lane * 4 + q];
                nxt[4*q] = t.x; nxt[4*q+1] = t.y; nxt[4*q+2] = t.z; nxt[4*q+3] = t.w;
            }
        }
        float accv[4];
        #pragma unroll
        for (int k = 0; k < 4; k++) {
            const int s = wid + (k << 3);         // strided slot, wave-uniform
            float acc0 = 0.0f, acc1 = 0.0f;
            if (s < i) {                          // wave-uniform
                #pragma unroll
                for (int e = 0; e < 8; e++) {
                    float d0 = m[e] - R[k][e];
                    float d1 = m[e + 8] - R[k][e + 8];
                    acc0 += d0 * d0;
                    acc1 += d1 * d1;
                }
            } else if (s == i) {                  // owner captures streamed row
                #pragma unroll
                for (int e = 0; e < 16; e++) R[k][e] = m[e];
            }
            accv[k] = acc0 + acc1;
        }
        float c = reduce4f(accv[0], accv[1], accv[2], accv[3], lane);
        int s_lane = wid + ((lane & 3) << 3);     // slot for this lane's sum
        if (lane < 4 && s_lane < i) { D[i][s_lane] = c; D[s_lane][i] = c; }

        if (i < NROWS - 1) {
            #pragma unroll
            for (int e = 0; e < 16; e++) m[e] = nxt[e];
        }
    }
    __syncthreads();

    // ---------- main merge loop: 3 barriers/step ----------
    int p = 0;
    #pragma unroll 1
    for (int step = 0; step < NSTEPS; step++) {
        const int n = NROWS - step;
        int* idx  = idxbuf[p];
        int* nidx = idxbuf[p ^ 1];
        const uint32_t M = 0xFFFFFFFFu / (uint32_t)n + 1u;  // exact for flat<2^27

        // --- argmin: one live-position pair per thread (static table) ---
        unsigned long long bk = ~0ull;
        if (tid < 496) {
            const int pr = pairTab[tid];
            const int i2 = pr >> 8, j2 = pr & 255;          // i2 < j2 < 32
            if (j2 < n) {                                   // both alive
                const int si = idx[i2], sj = idx[j2];
                uint32_t d2b = __float_as_uint(D[si][sj]);  // d2>=0: monotone bits
                bk = ((unsigned long long)d2b << 10) | (unsigned)(i2 * n + j2);
            }
        }
        #pragma unroll
        for (int off = 1; off < 64; off <<= 1) {
            unsigned long long ov = __shfl_xor(bk, off);
            bk = (ov < bk) ? ov : bk;
        }
        if (lane == 0) atomicMin(&wmin[step & 1], bk);      // 8 staggered, pre-B1
        __syncthreads();                                   // B1

        // --- decode: single broadcast load (atomic min == tree min, exact) ---
        bk = wmin[step & 1];
        const int bp  = (int)(bk & 1023u);
        const int a   = (int)__umulhi((uint32_t)bp, M);
        const int bbj = bp - a * n;
        const int sa  = idx[a], sb = idx[bbj];
        const int deadSlot = (a == 1) ? idx[0] : sa;

        // --- conv partials by owner waves, from registers, float4-packed LDS ---
        #pragma unroll
        for (int k = 0; k < 4; k++) {
            const int s = bs[k];                           // register, wave-uniform
            if (s == sa || s == sb) {
                float hl = __shfl_up(R[k][15], 1);  if (lane == 0)  hl = 0.0f;
                float hr = __shfl_down(R[k][0], 1); if (lane == 63) hr = 0.0f;
                float4* dst = (s == sa) ? mA4 : mB4;
                const float c0 = (s == sa) ? w00 : w10;
                const float c1 = (s == sa) ? w01 : w11;
                const float c2 = (s == sa) ? w02 : w12;
                #pragma unroll
                for (int q = 0; q < 4; q++) {
                    float vv[4];
                    #pragma unroll
                    for (int j = 0; j < 4; j++) {
                        const int e = 4 * q + j;
                        float xm1 = (e == 0)  ? hl : R[k][e - 1];
                        float xp1 = (e == 15) ? hr : R[k][e + 1];
                        vv[j] = c0 * xm1 + c1 * R[k][e] + c2 * xp1;
                    }
                    dst[q * 64 + lane] = make_float4(vv[0], vv[1], vv[2], vv[3]);
                }
            }
        }
        // --- bookkeeping: next logical order (merged keeps slot id sb) ---
        if (tid == 0) nidx[0] = sb;
        if (tid >= 1 && tid < n - 1) {
            int kk = tid + 1;
            int src = (kk == bbj) ? 1 : ((kk == a) ? 0 : kk);
            nidx[tid] = idx[src];
        }
        __syncthreads();                                   // B2

        // reset this step's accumulator for step+2 (all decode reads were
        // pre-B2; next atomics to it are post-B3 of step+1 — barrier-ordered)
        if (tid == 0) wmin[step & 1] = ~0ull;

        // --- finalize m: 4x ds_read_b128 per array, conflict-free ---
        #pragma unroll
        for (int q = 0; q < 4; q++) {
            float4 va = mA4[q * 64 + lane];
            float4 vb = mB4[q * 64 + lane];
            float v0 = cb + va.x + vb.x;
            float v1 = cb + va.y + vb.y;
            float v2 = cb + va.z + vb.z;
            float v3 = cb + va.w + vb.w;
            m[4*q+0] = v0 > 0.0f ? v0 : 0.0f;
            m[4*q+1] = v1 > 0.0f ? v1 : 0.0f;
            m[4*q+2] = v2 > 0.0f ? v2 : 0.0f;
            m[4*q+3] = v3 > 0.0f ? v3 : 0.0f;
        }
        // owner(sb): bank <- m; owner(deadSlot): kill bank; dists vs live banks
        float accv[4]; int slv[4];
        #pragma unroll
        for (int k = 0; k < 4; k++) {
            int s = bs[k];
            if (s == sb) {                                 // wave-uniform
                #pragma unroll
                for (int e = 0; e < 16; e++) R[k][e] = m[e];
            }
            if (s == deadSlot) {                           // wave-uniform
                bs[k] = -1;
                s = -1;
            }
            const int live = (s >= 0 && s != sb) ? s : -1;
            slv[k] = live;
            float acc0 = 0.0f, acc1 = 0.0f;
            if (live >= 0) {                               // wave-uniform
                #pragma unroll
                for (int e = 0; e < 8; e++) {
                    float d0 = m[e] - R[k][e];
                    float d1 = m[e + 8] - R[k][e + 8];
                    acc0 += d0 * d0;
                    acc1 += d1 * d1;
                }
            }
            accv[k] = acc0 + acc1;
        }
        // joint reduce: lane l holds sum for bank (l&3)
        float c = reduce4f(accv[0], accv[1], accv[2], accv[3], lane);
        int s_lane = slv[0];
        s_lane = ((lane & 3) == 1) ? slv[1] : s_lane;
        s_lane = ((lane & 3) == 2) ? slv[2] : s_lane;
        s_lane = ((lane & 3) == 3) ? slv[3] : s_lane;
        if (lane < 4 && s_lane >= 0) {
            D[sb][s_lane] = c; D[s_lane][sb] = c;
        }
        __syncthreads();                                   // B3
        p ^= 1;
    }

    // final merged row is in m (all waves); wave 0 writes it
    if (wid == 0) {
        float4* od = (float4*)(out + (size_t)b * CDIM);
        #pragma unroll
        for (int q = 0; q < 4; q++)
            od[lane * 4 + q] = make_float4(m[4*q], m[4*q+1], m[4*q+2], m[4*q+3]);
    }
}

extern "C" void kernel_launch(void* const* d_in, const int* in_sizes, int n_in,
                              void* d_out, int out_size, void* d_ws, size_t ws_size,
                              hipStream_t stream) {
    const float* x  = (const float*)d_in[0]; // fp32 (512,32,1024)
    const float* w  = (const float*)d_in[1]; // fp32 (1,2,3)
    const float* cb = (const float*)d_in[2]; // fp32 (1,)
    float* out = (float*)d_out;              // fp32 (512,1024)
    (void)d_ws; (void)ws_size; (void)in_sizes; (void)n_in; (void)out_size;

    hipLaunchKernelGGL(merge_tree_kernel, dim3(BATCH), dim3(BDIM), 0, stream,
                       x, w, cb, out);
}

// Round 15
// 192.439 us; speedup vs baseline: 1.4330x; 1.0463x over previous
//
#include <hip/hip_runtime.h>
#include <stdint.h>

#define BDIM    512                   // 8 waves per batch
#define NROWS   32
#define CDIM    1024
#define NSTEPS  31
#define BATCH   512

// One 512-thread block (8 waves) per batch. ALL alive rows live in REGISTERS:
// wave w owns 4 "banks" k=0..3 holding slots s = w + 8k (strided ownership,
// balanced init); lane holds elements [lane*16..+15]. Bank->slot map bs[4]
// in REGISTERS. Merged row overwrites slot sb's bank and D-row. The OTHER
// dead slot is idx[a] normally but idx[0] when a==1 (reference quirk).
//
// Argmin: static 496-pair triangle table (one pair/thread, filter j<n).
// Wave reduction is a fp32-MIN butterfly with DPP for all intra-row stages
// (ror:8, ror:4, quad 0x4E = xor2, quad 0xB1 = xor1; VALU-speed) + 2
// ds-shuffles (xor16/32); fmin is exact. Tie-break: pairTab is (i,j)-lex
// => flat = i*n+j is MONOTONE in tid => key u64 = (d2_bits<<10)|tid picks
// the same winner as reference (d2, flat); winning lane found by ballot.
// Lane 0 atomicMin's into wmin[step&1]; decode after B1 = wmin load +
// pairTab[tid] load (a,bbj direct — umulhi/M deleted). wmin dbl-buffered,
// reset by tid 0 in phase B (barrier-ordered, next atomics at step+2).
//
// reduce4f: 5 of 7 stages DPP (xor1/xor2 quad-perms exact; xor4/xor8 ->
// ror:4/ror:8, same 4-class sums, reassociation ~1e-7 — an order below the
// validated fp64->fp32 + split-chain changes => decisions unchanged).
//
// ALL distance math fp32 (validated: margins >> fp32 noise). conv partials
// float4-packed, lane-aligned (4x ds_read_b128 per array). 3 barriers/step
// — proven minimal (R6/R12 2-barrier designs both regressed).
// No global reads after init.
template<int CTRL>
__device__ __forceinline__ float dppf(float v) {
    int vi = __float_as_int(v);
    return __int_as_float(__builtin_amdgcn_update_dpp(vi, vi, CTRL, 0xF, 0xF, true));
}

__device__ __forceinline__ float reduce4f(float a0, float a1, float a2, float a3, int lane) {
    // Joint wave-sum of 4 fp32 values; lane l ends holding S_{l&3}.
    float t, r, b01, b23, c;
    t = (lane & 1) ? a0 : a1; r = (lane & 1) ? a1 : a0; b01 = r + dppf<0xB1>(t);  // xor1
    t = (lane & 1) ? a2 : a3; r = (lane & 1) ? a3 : a2; b23 = r + dppf<0xB1>(t);  // xor1
    t = (lane & 2) ? b01 : b23; r = (lane & 2) ? b23 : b01; c = r + dppf<0x4E>(t); // xor2
    c += dppf<0x124>(c);              // ror:4  — class {l, l+4}
    c += dppf<0x128>(c);              // ror:8  — + {l+8, l+12}
    c += __shfl_xor(c, 16);
    c += __shfl_xor(c, 32);
    return c;
}

__global__ __launch_bounds__(BDIM, 4)
void merge_tree_kernel(const float* __restrict__ xin,  // B*32*1024 fp32
                       const float* __restrict__ wz,   // 6 fp32 (1,2,3)
                       const float* __restrict__ bz,   // 1 fp32
                       float* __restrict__ out)        // B*1024 fp32
{
    const int b    = blockIdx.x;
    const int tid  = threadIdx.x;
    const int lane = tid & 63;
    const int wid  = tid >> 6;        // 0..7

    const float* xb = xin + (size_t)b * NROWS * CDIM;

    __shared__ float  D[NROWS][NROWS + 1];   // slot-indexed d2, fp32, padded
    __shared__ float4 mA4[4 * 64];           // conv partial (ch0), [q][lane] float4
    __shared__ float4 mB4[4 * 64];           // conv partial (ch1), [q][lane] float4
    __shared__ int    idxbuf[2][NROWS];      // logical pos -> slot (dbl-buffered)
    __shared__ int    pairTab[496];          // static triangle (i<<8)|j, i<j<32
    __shared__ unsigned long long wmin[2];   // argmin accumulator (dbl-buffered)

    const float w00 = wz[0], w01 = wz[1], w02 = wz[2];
    const float w10 = wz[3], w11 = wz[4], w12 = wz[5];
    const float cb  = bz[0];

    float R[4][16];                   // 4 owned rows (64 VGPRs)
    float m[16];                      // streamed / merged row
    float nxt[16];                    // init prefetch buffer
    int   bs[4];                      // bank -> slot (own wave only), -1 dead
    #pragma unroll
    for (int k = 0; k < 4; k++) bs[k] = wid + (k << 3);   // strided ownership

    if (tid < NROWS) {
        idxbuf[0][tid] = tid;
        // build static triangle table: row i entries at 31i - i(i-1)/2
        int i = tid;
        int base = 31 * i - (i * (i - 1)) / 2;
        for (int j = i + 1; j < NROWS; j++)
            pairTab[base + (j - i - 1)] = (i << 8) | j;
    }
    if (tid < 2) wmin[tid] = ~0ull;

    // ---------- single-pass init: stream row i, owner captures, dist vs s<i ----------
    {
        const float4* src = (const float4*)xb;    // row 0
        #pragma unroll
        for (int q = 0; q < 4; q++) {
            float4 t = src[lane * 4 + q];
            m[4*q] = t.x; m[4*q+1] = t.y; m[4*q+2] = t.z; m[4*q+3] = t.w;
        }
    }
    #pragma unroll 1
    for (int i = 0; i < NROWS; i++) {
        if (i < NROWS - 1) {                      // prefetch row i+1
            const float4* src = (const float4*)(xb + (size_t)(i + 1) * CDIM);
            #pragma unroll
            for (int q = 0; q < 4; q++) {
                float4 t = src[lane * 4 + q];
                nxt[4*q] = t.x; nxt[4*q+1] = t.y; nxt[4*q+2] = t.z; nxt[4*q+3] = t.w;
            }
        }
        float accv[4];
        #pragma unroll
        for (int k = 0; k < 4; k++) {
            const int s = wid + (k << 3);         // strided slot, wave-uniform
            float acc0 = 0.0f, acc1 = 0.0f;
            if (s < i) {                          // wave-uniform
                #pragma unroll
                for (int e = 0; e < 8; e++) {
                    float d0 = m[e] - R[k][e];
                    float d1 = m[e + 8] - R[k][e + 8];
                    acc0 += d0 * d0;
                    acc1 += d1 * d1;
                }
            } else if (s == i) {                  // owner captures streamed row
                #pragma unroll
                for (int e = 0; e < 16; e++) R[k][e] = m[e];
            }
            accv[k] = acc0 + acc1;
        }
        float c = reduce4f(accv[0], accv[1], accv[2], accv[3], lane);
        int s_lane = wid + ((lane & 3) << 3);     // slot for this lane's sum
        if (lane < 4 && s_lane < i) { D[i][s_lane] = c; D[s_lane][i] = c; }

        if (i < NROWS - 1) {
            #pragma unroll
            for (int e = 0; e < 16; e++) m[e] = nxt[e];
        }
    }
    __syncthreads();

    // ---------- main merge loop: 3 barriers/step ----------
    int p = 0;
    #pragma unroll 1
    for (int step = 0; step < NSTEPS; step++) {
        const int n = NROWS - step;
        int* idx  = idxbuf[p];
        int* nidx = idxbuf[p ^ 1];

        // --- argmin: one live-position pair per thread (static table) ---
        float dloc = __int_as_float(0x7F800000);            // +inf for invalid
        if (tid < 496) {
            const int pr = pairTab[tid];
            const int i2 = pr >> 8, j2 = pr & 255;          // i2 < j2 < 32
            if (j2 < n)                                     // both alive
                dloc = D[idx[i2]][idx[j2]];
        }
        // wave-wide exact fp32 min: 4 DPP stages + 2 ds-shuffles
        float v = dloc;
        v = fminf(v, dppf<0x128>(v));                       // ror:8
        v = fminf(v, dppf<0x124>(v));                       // ror:4
        v = fminf(v, dppf<0x4E>(v));                        // xor2
        v = fminf(v, dppf<0xB1>(v));                        // xor1
        { float o = __shfl_xor(v, 16); v = fminf(v, o); }
        { float o = __shfl_xor(v, 32); v = fminf(v, o); }
        unsigned long long eq = __ballot(dloc == v);        // ties: lowest tid = lowest flat
        if (lane == 0) {
            int lowlane = __ffsll(eq) - 1;
            unsigned long long key =
                ((unsigned long long)__float_as_uint(v) << 10)
                | (unsigned)((wid << 6) | lowlane);
            atomicMin(&wmin[step & 1], key);                // 8 staggered, pre-B1
        }
        __syncthreads();                                   // B1

        // --- decode: wmin load + pairTab broadcast (no division) ---
        unsigned long long bk = wmin[step & 1];
        const int prw = pairTab[(int)(bk & 1023u)];
        const int a   = prw >> 8;
        const int bbj = prw & 255;
        const int sa  = idx[a], sb = idx[bbj];
        const int deadSlot = (a == 1) ? idx[0] : sa;

        // --- conv partials by owner waves, from registers, float4-packed LDS ---
        #pragma unroll
        for (int k = 0; k < 4; k++) {
            const int s = bs[k];                           // register, wave-uniform
            if (s == sa || s == sb) {
                float hl = __shfl_up(R[k][15], 1);  if (lane == 0)  hl = 0.0f;
                float hr = __shfl_down(R[k][0], 1); if (lane == 63) hr = 0.0f;
                float4* dst = (s == sa) ? mA4 : mB4;
                const float c0 = (s == sa) ? w00 : w10;
                const float c1 = (s == sa) ? w01 : w11;
                const float c2 = (s == sa) ? w02 : w12;
                #pragma unroll
                for (int q = 0; q < 4; q++) {
                    float vv[4];
                    #pragma unroll
                    for (int j = 0; j < 4; j++) {
                        const int e = 4 * q + j;
                        float xm1 = (e == 0)  ? hl : R[k][e - 1];
                        float xp1 = (e == 15) ? hr : R[k][e + 1];
                        vv[j] = c0 * xm1 + c1 * R[k][e] + c2 * xp1;
                    }
                    dst[q * 64 + lane] = make_float4(vv[0], vv[1], vv[2], vv[3]);
                }
            }
        }
        // --- bookkeeping: next logical order (merged keeps slot id sb) ---
        if (tid == 0) nidx[0] = sb;
        if (tid >= 1 && tid < n - 1) {
            int kk = tid + 1;
            int src = (kk == bbj) ? 1 : ((kk == a) ? 0 : kk);
            nidx[tid] = idx[src];
        }
        __syncthreads();                                   // B2

        // reset this step's accumulator for step+2 (all decode reads were
        // pre-B2; next atomics to it are post-B3 of step+1 — barrier-ordered)
        if (tid == 0) wmin[step & 1] = ~0ull;

        // --- finalize m: 4x ds_read_b128 per array, conflict-free ---
        #pragma unroll
        for (int q = 0; q < 4; q++) {
            float4 va = mA4[q * 64 + lane];
            float4 vb = mB4[q * 64 + lane];
            float v0 = cb + va.x + vb.x;
            float v1 = cb + va.y + vb.y;
            float v2 = cb + va.z + vb.z;
            float v3 = cb + va.w + vb.w;
            m[4*q+0] = v0 > 0.0f ? v0 : 0.0f;
            m[4*q+1] = v1 > 0.0f ? v1 : 0.0f;
            m[4*q+2] = v2 > 0.0f ? v2 : 0.0f;
            m[4*q+3] = v3 > 0.0f ? v3 : 0.0f;
        }
        // owner(sb): bank <- m; owner(deadSlot): kill bank; dists vs live banks
        float accv[4]; int slv[4];
        #pragma unroll
        for (int k = 0; k < 4; k++) {
            int s = bs[k];
            if (s == sb) {                                 // wave-uniform
                #pragma unroll
                for (int e = 0; e < 16; e++) R[k][e] = m[e];
            }
            if (s == deadSlot) {                           // wave-uniform
                bs[k] = -1;
                s = -1;
            }
            const int live = (s >= 0 && s != sb) ? s : -1;
            slv[k] = live;
            float acc0 = 0.0f, acc1 = 0.0f;
            if (live >= 0) {                               // wave-uniform
                #pragma unroll
                for (int e = 0; e < 8; e++) {
                    float d0 = m[e] - R[k][e];
                    float d1 = m[e + 8] - R[k][e + 8];
                    acc0 += d0 * d0;
                    acc1 += d1 * d1;
                }
            }
            accv[k] = acc0 + acc1;
        }
        // joint reduce: lane l holds sum for bank (l&3)
        float c = reduce4f(accv[0], accv[1], accv[2], accv[3], lane);
        int s_lane = slv[0];
        s_lane = ((lane & 3) == 1) ? slv[1] : s_lane;
        s_lane = ((lane & 3) == 2) ? slv[2] : s_lane;
        s_lane = ((lane & 3) == 3) ? slv[3] : s_lane;
        if (lane < 4 && s_lane >= 0) {
            D[sb][s_lane] = c; D[s_lane][sb] = c;
        }
        __syncthreads();                                   // B3
        p ^= 1;
    }

    // final merged row is in m (all waves); wave 0 writes it
    if (wid == 0) {
        float4* od = (float4*)(out + (size_t)b * CDIM);
        #pragma unroll
        for (int q = 0; q < 4; q++)
            od[lane * 4 + q] = make_float4(m[4*q], m[4*q+1], m[4*q+2], m[4*q+3]);
    }
}

extern "C" void kernel_launch(void* const* d_in, const int* in_sizes, int n_in,
                              void* d_out, int out_size, void* d_ws, size_t ws_size,
                              hipStream_t stream) {
    const float* x  = (const float*)d_in[0]; // fp32 (512,32,1024)
    const float* w  = (const float*)d_in[1]; // fp32 (1,2,3)
    const float* cb = (const float*)d_in[2]; // fp32 (1,)
    float* out = (float*)d_out;              // fp32 (512,1024)
    (void)d_ws; (void)ws_size; (void)in_sizes; (void)n_in; (void)out_size;

    hipLaunchKernelGGL(merge_tree_kernel, dim3(BATCH), dim3(BDIM), 0, stream,
                       x, w, cb, out);
}